// Round 8
// baseline (166.559 us; speedup 1.0000x reference)
//
#include <hip/hip_runtime.h>

// SlidingWindowAttention: B=2, L=2048, D=1024, H=16, hd=64, W=256.
// I/O f32; internal bf16 MFMA with f32 accum.
#define DIM 1024
#define NH  16
#define HD  64
#define BB  2
#define LL  2048
#define WIN 256
#define MM  (BB * LL)     // 4096 rows
#define NQKV (3 * DIM)    // 3072 fused QKV output cols
#define SEG  (DIM * DIM)

typedef __bf16 bf16x8 __attribute__((ext_vector_type(8)));
typedef float  f32x4  __attribute__((ext_vector_type(4)));
typedef unsigned short u16x8 __attribute__((ext_vector_type(8)));

__device__ __forceinline__ unsigned short f2bf(float f) {
    union { float f; unsigned int i; } v; v.f = f;
    unsigned int r = v.i + 0x7fffu + ((v.i >> 16) & 1u);  // RNE
    return (unsigned short)(r >> 16);
}
__device__ __forceinline__ bf16x8 load8bf(const unsigned short* p) {
    uint4 u = *reinterpret_cast<const uint4*>(p);
    return __builtin_bit_cast(bf16x8, u);
}
__device__ __forceinline__ void gll16(const void* g, void* l) {
    __builtin_amdgcn_global_load_lds(
        (const __attribute__((address_space(1))) unsigned int*)g,
        (__attribute__((address_space(3))) unsigned int*)l, 16, 0, 0);
}

// ---------------------------------------------------------------------------
// Kernel 0: f32 -> bf16 conversion/packing.
// ---------------------------------------------------------------------------
__global__ __launch_bounds__(256) void convert_inputs(
    const float* __restrict__ x,
    const float* __restrict__ Wq, const float* __restrict__ Wk,
    const float* __restrict__ Wv, const float* __restrict__ Wo,
    unsigned short* __restrict__ xb,
    unsigned short* __restrict__ wqkv,
    unsigned short* __restrict__ wob)
{
    const int y = blockIdx.y;
    const size_t base = ((size_t)blockIdx.x * 256 + threadIdx.x) * 8;
    const float* src; unsigned short* dst;
    if (y < 4)       { src = x + (size_t)y * SEG;  dst = xb + (size_t)y * SEG; }
    else if (y == 4) { src = Wq; dst = wqkv; }
    else if (y == 5) { src = Wk; dst = wqkv + SEG; }
    else if (y == 6) { src = Wv; dst = wqkv + 2 * (size_t)SEG; }
    else             { src = Wo; dst = wob; }
    float4 a = ((const float4*)(src + base))[0];
    float4 b = ((const float4*)(src + base))[1];
    u16x8 r;
    r[0] = f2bf(a.x); r[1] = f2bf(a.y); r[2] = f2bf(a.z); r[3] = f2bf(a.w);
    r[4] = f2bf(b.x); r[5] = f2bf(b.y); r[6] = f2bf(b.z); r[7] = f2bf(b.w);
    *(u16x8*)(dst + base) = r;
}

// ---------------------------------------------------------------------------
// Kernel 1: fused QKV GEMM + RoPE. 128x128 tile, 4 waves (2x2), BK=64,
// launch_bounds(256,4) caps VGPR under 128. 8-chunk XOR swizzled staging.
// q,k -> [B,H,L,64] (RoPE fused); v -> [B,H,64,L] via 2-pass LDS transpose.
// ---------------------------------------------------------------------------
__global__ __launch_bounds__(256, 4) void qkv_gemm(
    const unsigned short* __restrict__ xb,
    const unsigned short* __restrict__ wqkv,
    const float* __restrict__ cosb, const float* __restrict__ sinb,
    unsigned short* __restrict__ qws, unsigned short* __restrict__ kws,
    unsigned short* __restrict__ vT)
{
    __shared__ __align__(16) unsigned short smem[2 * 128 * 64];  // As|Bs 32 KB
    unsigned short* As = smem;
    unsigned short* Bs = smem + 128 * 64;
    const int t = threadIdx.x;
    const int lane = t & 63, w = t >> 6;
    const int wm = w >> 1, wn = w & 1;
    const int lr = lane & 15, quad = lane >> 4;
    const int n0 = blockIdx.x * 128, m0 = blockIdx.y * 128;

    f32x4 acc[4][4];
    for (int i = 0; i < 4; i++) for (int j = 0; j < 4; j++) acc[i][j] = 0.0f;

    const int rsub = t >> 3;                 // 0..31
    const int csw  = (t & 7) ^ (rsub & 7);   // swizzled source chunk
    const int sw7  = lr & 7;                 // frag-read swizzle key

    for (int k0 = 0; k0 < DIM; k0 += 64) {
        __syncthreads();
        #pragma unroll
        for (int p = 0; p < 4; p++) {
            const int row = p * 32 + rsub;
            gll16(xb   + (size_t)(m0 + row) * DIM + k0 + csw * 8,
                  &As[p * 2048 + t * 8]);
            gll16(wqkv + (size_t)(n0 + row) * DIM + k0 + csw * 8,
                  &Bs[p * 2048 + t * 8]);
        }
        __syncthreads();
        #pragma unroll
        for (int kk = 0; kk < 2; kk++) {
            bf16x8 af[4], bfr[4];
            #pragma unroll
            for (int mi = 0; mi < 4; mi++) {
                const int R = wm * 64 + mi * 16 + lr;
                af[mi] = load8bf(&As[R * 64 + (((kk * 4 + quad) ^ sw7) * 8)]);
            }
            #pragma unroll
            for (int ni = 0; ni < 4; ni++) {
                const int R = wn * 64 + ni * 16 + lr;
                bfr[ni] = load8bf(&Bs[R * 64 + (((kk * 4 + quad) ^ sw7) * 8)]);
            }
            #pragma unroll
            for (int mi = 0; mi < 4; mi++)
                #pragma unroll
                for (int ni = 0; ni < 4; ni++)
                    acc[mi][ni] = __builtin_amdgcn_mfma_f32_16x16x32_bf16(
                        af[mi], bfr[ni], acc[mi][ni], 0, 0, 0);
        }
    }

    const int ng = n0 + wn * 64;
    const int which = ng >> 10;            // 0=q 1=k 2=v (block-uniform)
    const int h = (ng & (DIM - 1)) >> 6;

    if (which == 2) {
        // ---- v: transpose 64x64 tile -> vT[B,H,64,L], 2 passes of 32 d-rows
        __syncthreads();
        unsigned short* T = smem + w * 2048;
        const int token0 = m0 + wm * 64;
        const int b  = token0 >> 11;
        const int lg = (token0 & (LL - 1)) + (lane & 7) * 8;
        #pragma unroll
        for (int p = 0; p < 2; p++) {
            #pragma unroll
            for (int ni = 2 * p; ni < 2 * p + 2; ni++) {
                const int dl = (ni & 1) * 16 + lr;
                const int g4 = (dl & 7) << 2;
                #pragma unroll
                for (int mi = 0; mi < 4; mi++)
                    #pragma unroll
                    for (int reg = 0; reg < 4; reg++) {
                        const int l = mi * 16 + quad * 4 + reg;
                        const int cw = (l >> 1) ^ g4;
                        T[dl * 64 + cw * 2 + (l & 1)] = f2bf(acc[mi][ni][reg]);
                    }
            }
            #pragma unroll
            for (int s = 0; s < 4; s++) {
                const int dl = s * 8 + (lane >> 3);
                const int d  = p * 32 + dl;
                const int g4 = (dl & 7) << 2;
                const int pd = ((lane & 7) * 4) ^ g4;
                uint4 val = *(const uint4*)&T[dl * 64 + pd * 2];
                *(uint4*)&vT[((size_t)(b * NH + h) * HD + d) * LL + lg] = val;
            }
        }
    } else {
        unsigned short* dst = (which == 0) ? qws : kws;
        #pragma unroll
        for (int mi = 0; mi < 4; mi++) {
            #pragma unroll
            for (int reg = 0; reg < 4; reg++) {
                const int row = m0 + wm * 64 + mi * 16 + quad * 4 + reg;
                const int b = row >> 11, l = row & (LL - 1);
                #pragma unroll
                for (int ni = 0; ni < 4; ni++) {
                    const int d = ni * 16 + lr;
                    const float c = cosb[l * HD + d];
                    const float s = sinb[l * HD + d];
                    const float partner = (d < 32) ? -acc[mi][ni + 2][reg]
                                                   :  acc[mi][ni - 2][reg];
                    dst[((size_t)(b * NH + h) * LL + l) * HD + d] =
                        f2bf(acc[mi][ni][reg] * c + partner * s);
                }
            }
        }
    }
}

// ---------------------------------------------------------------------------
// Kernel 2: sliding-window attention. 4-wave block per 64 queries of one
// (b,h). K-span (320 keys) staged once in 40 KB LDS, shared by all 4 waves.
// P gets its OWN 37.9 KB region: scores go exp'd -> bf16 -> LDS inside the
// score loop (NO sc[17] register array -- that spilled under the 128-VGPR
// cap and cost ~140 MB of scratch traffic). P is wave-private (write+read
// by same wave, ordered by lgkmcnt) -> only ONE barrier in the kernel.
// LDS 78.8 KB -> 2 blocks/CU; launch_bounds(256,2) -> no VGPR pressure.
// ---------------------------------------------------------------------------
#define SW_SPAN 320
#define SSTRIDE 296   // u16; 16B-aligned rows
__global__ __launch_bounds__(256, 2) void swa_attn(
    const unsigned short* __restrict__ qws,
    const unsigned short* __restrict__ kws,
    const unsigned short* __restrict__ vT,
    unsigned short* __restrict__ aout)
{
    __shared__ __align__(16) unsigned short Ks[SW_SPAN * 64];        // 40 KB
    __shared__ __align__(16) unsigned short Pball[4 * 16 * SSTRIDE]; // 37.9 KB

    const int t = threadIdx.x;
    const int lane = t & 63, w = t >> 6;
    const int qb = blockIdx.x, h = blockIdx.y, b = blockIdx.z;
    const int q0 = qb * 64;
    const int base_key = q0 - WIN;

    const int lr = lane & 15, quad = lane >> 4, ko = quad * 8;
    const size_t base = ((size_t)(b * NH + h)) * LL * HD;
    const unsigned short* Q  = qws + base;
    const unsigned short* K  = kws + base;
    const unsigned short* VT = vT + base;     // [64][LL]

    // ---- stage K[320][64], 8-chunk swizzle ----
    {
        const int rsub = t >> 3;
        const int csw  = (t & 7) ^ (rsub & 7);
        #pragma unroll
        for (int p = 0; p < 10; p++) {
            const int j = min(max(base_key + p * 32 + rsub, 0), LL - 1);
            gll16(K + (size_t)j * HD + csw * 8, &Ks[p * 2048 + t * 8]);
        }
    }
    const int i0 = q0 + w * 16;
    const bf16x8 qa0 = load8bf(Q + (size_t)(i0 + lr) * HD + ko);
    const bf16x8 qa1 = load8bf(Q + (size_t)(i0 + lr) * HD + 32 + ko);
    __syncthreads();                          // the only barrier

    unsigned short* Pb = Pball + w * (16 * SSTRIDE);  // wave-private P
    float rowsum[4] = {0.f, 0.f, 0.f, 0.f};

    #pragma unroll
    for (int kt = 0; kt < 17; kt++) {
        const int R = w * 16 + kt * 16 + lr;
        const bf16x8 kb0 = load8bf(&Ks[R * 64 + ((quad       ^ (R & 7)) * 8)]);
        const bf16x8 kb1 = load8bf(&Ks[R * 64 + (((quad + 4) ^ (R & 7)) * 8)]);
        f32x4 s = 0.0f;
        s = __builtin_amdgcn_mfma_f32_16x16x32_bf16(qa0, kb0, s, 0, 0, 0);
        s = __builtin_amdgcn_mfma_f32_16x16x32_bf16(qa1, kb1, s, 0, 0, 0);
        #pragma unroll
        for (int reg = 0; reg < 4; reg++) {
            const int i = i0 + quad * 4 + reg;
            const int j = base_key + w * 16 + kt * 16 + lr;
            const bool valid = (j >= 0) && (j <= i) && (j >= i - WIN);
            const float e = valid ? __expf(s[reg] * 0.125f) : 0.0f;
            rowsum[reg] += e;
            Pb[(quad * 4 + reg) * SSTRIDE + kt * 16 + lr] = f2bf(e);
        }
    }
    #pragma unroll
    for (int r = 0; r < 4; r++)               // zero-pad cols [272, 288)
        Pb[(quad * 4 + r) * SSTRIDE + 272 + lr] = 0;

    float inv[4];
    #pragma unroll
    for (int reg = 0; reg < 4; reg++) {       // 16-lane butterfly within quad
        float s = rowsum[reg];
        s += __shfl_xor(s, 1); s += __shfl_xor(s, 2);
        s += __shfl_xor(s, 4); s += __shfl_xor(s, 8);
        inv[reg] = 1.0f / s;
    }

    f32x4 o[4];
    #pragma unroll
    for (int nt = 0; nt < 4; nt++) o[nt] = 0.0f;

    #pragma unroll
    for (int kc = 0; kc < 9; kc++) {
        const bf16x8 pa = load8bf(&Pb[lr * SSTRIDE + kc * 32 + ko]);
        int kb = base_key + w * 16 + kc * 32 + ko;
        kb = min(max(kb, 0), LL - 8);         // clamp touches only P==0 cols
        bf16x8 bv[4];
        #pragma unroll
        for (int nt = 0; nt < 4; nt++)
            bv[nt] = load8bf(VT + (size_t)(nt * 16 + lr) * LL + kb);
        #pragma unroll
        for (int nt = 0; nt < 4; nt++)
            o[nt] = __builtin_amdgcn_mfma_f32_16x16x32_bf16(pa, bv[nt], o[nt], 0, 0, 0);
    }

    #pragma unroll
    for (int nt = 0; nt < 4; nt++) {
        #pragma unroll
        for (int reg = 0; reg < 4; reg++) {
            const int i = i0 + quad * 4 + reg;
            const int d = nt * 16 + lr;
            aout[((size_t)(b * LL + i)) * DIM + h * HD + d] =
                f2bf(o[nt][reg] * inv[reg]);
        }
    }
}

// ---------------------------------------------------------------------------
// Kernel 3: output projection. 128(M)x64(N) tiles, BK=64 (16 barriers),
// swizzled staging, launch_bounds(256,4). Wave = 64M x 32N.
// ---------------------------------------------------------------------------
__global__ __launch_bounds__(256, 4) void out_gemm(
    const unsigned short* __restrict__ A,
    const unsigned short* __restrict__ Wob,
    float* __restrict__ out)
{
    __shared__ __align__(16) unsigned short smem[128 * 64 + 64 * 64];  // 24 KB
    unsigned short* As = smem;
    unsigned short* Bs = smem + 128 * 64;
    const int t = threadIdx.x;
    const int lane = t & 63, w = t >> 6;
    const int wm = w >> 1, wn = w & 1;
    const int lr = lane & 15, quad = lane >> 4;
    const int n0 = blockIdx.x * 64, m0 = blockIdx.y * 128;

    f32x4 acc[4][2];
    for (int i = 0; i < 4; i++) for (int j = 0; j < 2; j++) acc[i][j] = 0.0f;

    const int rsub = t >> 3;
    const int csw  = (t & 7) ^ (rsub & 7);
    const int sw7  = lr & 7;

    for (int k0 = 0; k0 < DIM; k0 += 64) {
        __syncthreads();
        #pragma unroll
        for (int p = 0; p < 4; p++) {
            const int row = p * 32 + rsub;
            gll16(A + (size_t)(m0 + row) * DIM + k0 + csw * 8,
                  &As[p * 2048 + t * 8]);
        }
        #pragma unroll
        for (int p = 0; p < 2; p++) {
            const int row = p * 32 + rsub;
            gll16(Wob + (size_t)(n0 + row) * DIM + k0 + csw * 8,
                  &Bs[p * 2048 + t * 8]);
        }
        __syncthreads();
        #pragma unroll
        for (int kk = 0; kk < 2; kk++) {
            bf16x8 af[4], bfr[2];
            #pragma unroll
            for (int mi = 0; mi < 4; mi++) {
                const int R = wm * 64 + mi * 16 + lr;
                af[mi] = load8bf(&As[R * 64 + (((kk * 4 + quad) ^ sw7) * 8)]);
            }
            #pragma unroll
            for (int ni = 0; ni < 2; ni++) {
                const int R = wn * 32 + ni * 16 + lr;
                bfr[ni] = load8bf(&Bs[R * 64 + (((kk * 4 + quad) ^ sw7) * 8)]);
            }
            #pragma unroll
            for (int mi = 0; mi < 4; mi++)
                #pragma unroll
                for (int ni = 0; ni < 2; ni++)
                    acc[mi][ni] = __builtin_amdgcn_mfma_f32_16x16x32_bf16(
                        af[mi], bfr[ni], acc[mi][ni], 0, 0, 0);
        }
    }

    #pragma unroll
    for (int mi = 0; mi < 4; mi++) {
        #pragma unroll
        for (int reg = 0; reg < 4; reg++) {
            const int row = m0 + wm * 64 + mi * 16 + quad * 4 + reg;
            #pragma unroll
            for (int ni = 0; ni < 2; ni++) {
                const int col = n0 + wn * 32 + ni * 16 + lr;
                out[(size_t)row * DIM + col] = acc[mi][ni][reg];
            }
        }
    }
}

extern "C" void kernel_launch(void* const* d_in, const int* in_sizes, int n_in,
                              void* d_out, int out_size, void* d_ws, size_t ws_size,
                              hipStream_t stream)
{
    const float* x    = (const float*)d_in[0];
    const float* cosb = (const float*)d_in[1];
    const float* sinb = (const float*)d_in[2];
    const float* Wq   = (const float*)d_in[3];
    const float* Wk   = (const float*)d_in[4];
    const float* Wv   = (const float*)d_in[5];
    const float* Wo   = (const float*)d_in[6];
    float* out = (float*)d_out;

    unsigned short* xb   = (unsigned short*)d_ws;
    unsigned short* wqkv = xb + (size_t)MM * DIM;
    unsigned short* wob  = wqkv + (size_t)NQKV * DIM;
    unsigned short* qws  = wob + (size_t)DIM * DIM;
    unsigned short* kws  = qws + (size_t)BB * NH * LL * HD;
    unsigned short* vT   = kws + (size_t)BB * NH * LL * HD;
    unsigned short* aws  = xb;   // alias: xb dead after qkv_gemm

    convert_inputs<<<dim3(SEG / (256 * 8), 8), 256, 0, stream>>>(
        x, Wq, Wk, Wv, Wo, xb, wqkv, wob);
    qkv_gemm<<<dim3(NQKV / 128, MM / 128), 256, 0, stream>>>(
        xb, wqkv, cosb, sinb, qws, kws, vT);
    swa_attn<<<dim3(LL / 64, NH, BB), 256, 0, stream>>>(qws, kws, vT, aws);
    out_gemm<<<dim3(DIM / 64, MM / 128), 256, 0, stream>>>(aws, wob, out);
}

// Round 9
// 164.800 us; speedup vs baseline: 1.0107x; 1.0107x over previous
//
#include <hip/hip_runtime.h>

// SlidingWindowAttention: B=2, L=2048, D=1024, H=16, hd=64, W=256.
// I/O f32; internal bf16 MFMA with f32 accum.
#define DIM 1024
#define NH  16
#define HD  64
#define BB  2
#define LL  2048
#define WIN 256
#define MM  (BB * LL)     // 4096 rows
#define NQKV (3 * DIM)    // 3072 fused QKV output cols
#define SEG  (DIM * DIM)

typedef __bf16 bf16x8 __attribute__((ext_vector_type(8)));
typedef float  f32x4  __attribute__((ext_vector_type(4)));
typedef unsigned short u16x8 __attribute__((ext_vector_type(8)));

__device__ __forceinline__ unsigned short f2bf(float f) {
    union { float f; unsigned int i; } v; v.f = f;
    unsigned int r = v.i + 0x7fffu + ((v.i >> 16) & 1u);  // RNE
    return (unsigned short)(r >> 16);
}
__device__ __forceinline__ bf16x8 load8bf(const unsigned short* p) {
    uint4 u = *reinterpret_cast<const uint4*>(p);
    return __builtin_bit_cast(bf16x8, u);
}
__device__ __forceinline__ void gll16(const void* g, void* l) {
    __builtin_amdgcn_global_load_lds(
        (const __attribute__((address_space(1))) unsigned int*)g,
        (__attribute__((address_space(3))) unsigned int*)l, 16, 0, 0);
}

// ---------------------------------------------------------------------------
// Kernel 0: f32 -> bf16 conversion/packing.
// ---------------------------------------------------------------------------
__global__ __launch_bounds__(256) void convert_inputs(
    const float* __restrict__ x,
    const float* __restrict__ Wq, const float* __restrict__ Wk,
    const float* __restrict__ Wv, const float* __restrict__ Wo,
    unsigned short* __restrict__ xb,
    unsigned short* __restrict__ wqkv,
    unsigned short* __restrict__ wob)
{
    const int y = blockIdx.y;
    const size_t base = ((size_t)blockIdx.x * 256 + threadIdx.x) * 8;
    const float* src; unsigned short* dst;
    if (y < 4)       { src = x + (size_t)y * SEG;  dst = xb + (size_t)y * SEG; }
    else if (y == 4) { src = Wq; dst = wqkv; }
    else if (y == 5) { src = Wk; dst = wqkv + SEG; }
    else if (y == 6) { src = Wv; dst = wqkv + 2 * (size_t)SEG; }
    else             { src = Wo; dst = wob; }
    float4 a = ((const float4*)(src + base))[0];
    float4 b = ((const float4*)(src + base))[1];
    u16x8 r;
    r[0] = f2bf(a.x); r[1] = f2bf(a.y); r[2] = f2bf(a.z); r[3] = f2bf(a.w);
    r[4] = f2bf(b.x); r[5] = f2bf(b.y); r[6] = f2bf(b.z); r[7] = f2bf(b.w);
    *(u16x8*)(dst + base) = r;
}

// ---------------------------------------------------------------------------
// Kernel 1: fused QKV GEMM + RoPE. 128x128 tile, 4 waves (2x2), BK=64,
// launch_bounds(256,4) caps VGPR under 128. 8-chunk XOR swizzled staging.
// q,k -> [B,H,L,64] (RoPE fused); v -> [B,H,64,L] via 2-pass LDS transpose.
// ---------------------------------------------------------------------------
__global__ __launch_bounds__(256, 4) void qkv_gemm(
    const unsigned short* __restrict__ xb,
    const unsigned short* __restrict__ wqkv,
    const float* __restrict__ cosb, const float* __restrict__ sinb,
    unsigned short* __restrict__ qws, unsigned short* __restrict__ kws,
    unsigned short* __restrict__ vT)
{
    __shared__ __align__(16) unsigned short smem[2 * 128 * 64];  // As|Bs 32 KB
    unsigned short* As = smem;
    unsigned short* Bs = smem + 128 * 64;
    const int t = threadIdx.x;
    const int lane = t & 63, w = t >> 6;
    const int wm = w >> 1, wn = w & 1;
    const int lr = lane & 15, quad = lane >> 4;
    const int n0 = blockIdx.x * 128, m0 = blockIdx.y * 128;

    f32x4 acc[4][4];
    for (int i = 0; i < 4; i++) for (int j = 0; j < 4; j++) acc[i][j] = 0.0f;

    const int rsub = t >> 3;                 // 0..31
    const int csw  = (t & 7) ^ (rsub & 7);   // swizzled source chunk
    const int sw7  = lr & 7;                 // frag-read swizzle key

    for (int k0 = 0; k0 < DIM; k0 += 64) {
        __syncthreads();
        #pragma unroll
        for (int p = 0; p < 4; p++) {
            const int row = p * 32 + rsub;
            gll16(xb   + (size_t)(m0 + row) * DIM + k0 + csw * 8,
                  &As[p * 2048 + t * 8]);
            gll16(wqkv + (size_t)(n0 + row) * DIM + k0 + csw * 8,
                  &Bs[p * 2048 + t * 8]);
        }
        __syncthreads();
        #pragma unroll
        for (int kk = 0; kk < 2; kk++) {
            bf16x8 af[4], bfr[4];
            #pragma unroll
            for (int mi = 0; mi < 4; mi++) {
                const int R = wm * 64 + mi * 16 + lr;
                af[mi] = load8bf(&As[R * 64 + (((kk * 4 + quad) ^ sw7) * 8)]);
            }
            #pragma unroll
            for (int ni = 0; ni < 4; ni++) {
                const int R = wn * 64 + ni * 16 + lr;
                bfr[ni] = load8bf(&Bs[R * 64 + (((kk * 4 + quad) ^ sw7) * 8)]);
            }
            #pragma unroll
            for (int mi = 0; mi < 4; mi++)
                #pragma unroll
                for (int ni = 0; ni < 4; ni++)
                    acc[mi][ni] = __builtin_amdgcn_mfma_f32_16x16x32_bf16(
                        af[mi], bfr[ni], acc[mi][ni], 0, 0, 0);
        }
    }

    const int ng = n0 + wn * 64;
    const int which = ng >> 10;            // 0=q 1=k 2=v (block-uniform)
    const int h = (ng & (DIM - 1)) >> 6;

    if (which == 2) {
        // ---- v: transpose 64x64 tile -> vT[B,H,64,L], 2 passes of 32 d-rows
        __syncthreads();
        unsigned short* T = smem + w * 2048;
        const int token0 = m0 + wm * 64;
        const int b  = token0 >> 11;
        const int lg = (token0 & (LL - 1)) + (lane & 7) * 8;
        #pragma unroll
        for (int p = 0; p < 2; p++) {
            #pragma unroll
            for (int ni = 2 * p; ni < 2 * p + 2; ni++) {
                const int dl = (ni & 1) * 16 + lr;
                const int g4 = (dl & 7) << 2;
                #pragma unroll
                for (int mi = 0; mi < 4; mi++)
                    #pragma unroll
                    for (int reg = 0; reg < 4; reg++) {
                        const int l = mi * 16 + quad * 4 + reg;
                        const int cw = (l >> 1) ^ g4;
                        T[dl * 64 + cw * 2 + (l & 1)] = f2bf(acc[mi][ni][reg]);
                    }
            }
            #pragma unroll
            for (int s = 0; s < 4; s++) {
                const int dl = s * 8 + (lane >> 3);
                const int d  = p * 32 + dl;
                const int g4 = (dl & 7) << 2;
                const int pd = ((lane & 7) * 4) ^ g4;
                uint4 val = *(const uint4*)&T[dl * 64 + pd * 2];
                *(uint4*)&vT[((size_t)(b * NH + h) * HD + d) * LL + lg] = val;
            }
        }
    } else {
        unsigned short* dst = (which == 0) ? qws : kws;
        #pragma unroll
        for (int mi = 0; mi < 4; mi++) {
            #pragma unroll
            for (int reg = 0; reg < 4; reg++) {
                const int row = m0 + wm * 64 + mi * 16 + quad * 4 + reg;
                const int b = row >> 11, l = row & (LL - 1);
                #pragma unroll
                for (int ni = 0; ni < 4; ni++) {
                    const int d = ni * 16 + lr;
                    const float c = cosb[l * HD + d];
                    const float s = sinb[l * HD + d];
                    const float partner = (d < 32) ? -acc[mi][ni + 2][reg]
                                                   :  acc[mi][ni - 2][reg];
                    dst[((size_t)(b * NH + h) * LL + l) * HD + d] =
                        f2bf(acc[mi][ni][reg] * c + partner * s);
                }
            }
        }
    }
}

// ---------------------------------------------------------------------------
// Kernel 2: sliding-window attention — ONLINE/streaming PV.
// 4-wave block per 64 queries of one (b,h). K-span (320 keys) staged once in
// 40 KB LDS, shared by all 4 waves. Per 32-key chunk: 2 score tiles -> exp ->
// bf16 into a tiny wave-private 16x32 P buffer (1.25 KB/wave) -> immediate
// PV MFMA with V streamed from vT. Wave-in-order LDS handles the P RAW (no
// barrier; precedent: round-8 P usage). Chunks are independent -> compiler
// overlaps chunk k+1 scores with chunk k V-loads. The kt=17 pad tile is
// masked to zero by j<=i (j >= i0+16 there); its K-row read is clamped.
// LDS 46 KB -> 3 blocks/CU (12 waves/CU). 1/sum folded into epilogue.
// ---------------------------------------------------------------------------
#define SW_SPAN 320
#define PSTR 40   // u16 row stride of chunk-P buffer (16B-aligned rows)
__global__ __launch_bounds__(256, 3) void swa_attn(
    const unsigned short* __restrict__ qws,
    const unsigned short* __restrict__ kws,
    const unsigned short* __restrict__ vT,
    unsigned short* __restrict__ aout)
{
    __shared__ __align__(16) unsigned short Ks[SW_SPAN * 64];   // 40 KB
    __shared__ __align__(16) unsigned short Pc[4][16][PSTR];    // 5 KB

    const int t = threadIdx.x;
    const int lane = t & 63, w = t >> 6;
    const int qb = blockIdx.x, h = blockIdx.y, b = blockIdx.z;
    const int q0 = qb * 64;
    const int base_key = q0 - WIN;

    const int lr = lane & 15, quad = lane >> 4, ko = quad * 8;
    const size_t base = ((size_t)(b * NH + h)) * LL * HD;
    const unsigned short* Q  = qws + base;
    const unsigned short* K  = kws + base;
    const unsigned short* VT = vT + base;     // [64][LL]

    // ---- stage K[320][64], 8-chunk swizzle ----
    {
        const int rsub = t >> 3;
        const int csw  = (t & 7) ^ (rsub & 7);
        #pragma unroll
        for (int p = 0; p < 10; p++) {
            const int j = min(max(base_key + p * 32 + rsub, 0), LL - 1);
            gll16(K + (size_t)j * HD + csw * 8, &Ks[p * 2048 + t * 8]);
        }
    }
    const int i0 = q0 + w * 16;               // wave's query tile
    const int wkey = i0 - WIN;                // wave's key-span start
    const bf16x8 qa0 = load8bf(Q + (size_t)(i0 + lr) * HD + ko);
    const bf16x8 qa1 = load8bf(Q + (size_t)(i0 + lr) * HD + 32 + ko);
    __syncthreads();                          // the only barrier

    float rowsum[4] = {0.f, 0.f, 0.f, 0.f};
    f32x4 o[4];
    #pragma unroll
    for (int nt = 0; nt < 4; nt++) o[nt] = 0.0f;

    #pragma unroll
    for (int kc = 0; kc < 9; kc++) {
        // ---- 2 score tiles -> exp -> bf16 chunk-P ----
        #pragma unroll
        for (int sub = 0; sub < 2; sub++) {
            const int kt = kc * 2 + sub;      // 0..17 (17 = pad tile)
            const int R = min(w * 16 + kt * 16 + lr, SW_SPAN - 1);
            const bf16x8 kb0 = load8bf(&Ks[R * 64 + ((quad       ^ (R & 7)) * 8)]);
            const bf16x8 kb1 = load8bf(&Ks[R * 64 + (((quad + 4) ^ (R & 7)) * 8)]);
            f32x4 s = 0.0f;
            s = __builtin_amdgcn_mfma_f32_16x16x32_bf16(qa0, kb0, s, 0, 0, 0);
            s = __builtin_amdgcn_mfma_f32_16x16x32_bf16(qa1, kb1, s, 0, 0, 0);
            #pragma unroll
            for (int reg = 0; reg < 4; reg++) {
                const int i = i0 + quad * 4 + reg;
                const int j = wkey + kt * 16 + lr;
                const bool valid = (j >= 0) && (j <= i) && (j >= i - WIN);
                const float e = valid ? __expf(s[reg] * 0.125f) : 0.0f;
                rowsum[reg] += e;
                Pc[w][quad * 4 + reg][sub * 16 + lr] = f2bf(e);
            }
        }
        // ---- immediate PV on this 32-key chunk ----
        const bf16x8 pa = load8bf(&Pc[w][lr][ko]);
        int kb = wkey + kc * 32 + ko;
        kb = min(max(kb, 0), LL - 8);         // clamp touches only P==0 cols
        bf16x8 bv[4];
        #pragma unroll
        for (int nt = 0; nt < 4; nt++)
            bv[nt] = load8bf(VT + (size_t)(nt * 16 + lr) * LL + kb);
        #pragma unroll
        for (int nt = 0; nt < 4; nt++)
            o[nt] = __builtin_amdgcn_mfma_f32_16x16x32_bf16(pa, bv[nt], o[nt], 0, 0, 0);
    }

    float inv[4];
    #pragma unroll
    for (int reg = 0; reg < 4; reg++) {       // 16-lane butterfly within quad
        float s = rowsum[reg];
        s += __shfl_xor(s, 1); s += __shfl_xor(s, 2);
        s += __shfl_xor(s, 4); s += __shfl_xor(s, 8);
        inv[reg] = 1.0f / s;
    }

    #pragma unroll
    for (int nt = 0; nt < 4; nt++) {
        #pragma unroll
        for (int reg = 0; reg < 4; reg++) {
            const int i = i0 + quad * 4 + reg;
            const int d = nt * 16 + lr;
            aout[((size_t)(b * LL + i)) * DIM + h * HD + d] =
                f2bf(o[nt][reg] * inv[reg]);
        }
    }
}

// ---------------------------------------------------------------------------
// Kernel 3: output projection. 128(M)x64(N) tiles, BK=64 (16 barriers),
// swizzled staging, launch_bounds(256,4). Wave = 64M x 32N.
// ---------------------------------------------------------------------------
__global__ __launch_bounds__(256, 4) void out_gemm(
    const unsigned short* __restrict__ A,
    const unsigned short* __restrict__ Wob,
    float* __restrict__ out)
{
    __shared__ __align__(16) unsigned short smem[128 * 64 + 64 * 64];  // 24 KB
    unsigned short* As = smem;
    unsigned short* Bs = smem + 128 * 64;
    const int t = threadIdx.x;
    const int lane = t & 63, w = t >> 6;
    const int wm = w >> 1, wn = w & 1;
    const int lr = lane & 15, quad = lane >> 4;
    const int n0 = blockIdx.x * 64, m0 = blockIdx.y * 128;

    f32x4 acc[4][2];
    for (int i = 0; i < 4; i++) for (int j = 0; j < 2; j++) acc[i][j] = 0.0f;

    const int rsub = t >> 3;
    const int csw  = (t & 7) ^ (rsub & 7);
    const int sw7  = lr & 7;

    for (int k0 = 0; k0 < DIM; k0 += 64) {
        __syncthreads();
        #pragma unroll
        for (int p = 0; p < 4; p++) {
            const int row = p * 32 + rsub;
            gll16(A + (size_t)(m0 + row) * DIM + k0 + csw * 8,
                  &As[p * 2048 + t * 8]);
        }
        #pragma unroll
        for (int p = 0; p < 2; p++) {
            const int row = p * 32 + rsub;
            gll16(Wob + (size_t)(n0 + row) * DIM + k0 + csw * 8,
                  &Bs[p * 2048 + t * 8]);
        }
        __syncthreads();
        #pragma unroll
        for (int kk = 0; kk < 2; kk++) {
            bf16x8 af[4], bfr[2];
            #pragma unroll
            for (int mi = 0; mi < 4; mi++) {
                const int R = wm * 64 + mi * 16 + lr;
                af[mi] = load8bf(&As[R * 64 + (((kk * 4 + quad) ^ sw7) * 8)]);
            }
            #pragma unroll
            for (int ni = 0; ni < 2; ni++) {
                const int R = wn * 32 + ni * 16 + lr;
                bfr[ni] = load8bf(&Bs[R * 64 + (((kk * 4 + quad) ^ sw7) * 8)]);
            }
            #pragma unroll
            for (int mi = 0; mi < 4; mi++)
                #pragma unroll
                for (int ni = 0; ni < 2; ni++)
                    acc[mi][ni] = __builtin_amdgcn_mfma_f32_16x16x32_bf16(
                        af[mi], bfr[ni], acc[mi][ni], 0, 0, 0);
        }
    }

    #pragma unroll
    for (int mi = 0; mi < 4; mi++) {
        #pragma unroll
        for (int reg = 0; reg < 4; reg++) {
            const int row = m0 + wm * 64 + mi * 16 + quad * 4 + reg;
            #pragma unroll
            for (int ni = 0; ni < 2; ni++) {
                const int col = n0 + wn * 32 + ni * 16 + lr;
                out[(size_t)row * DIM + col] = acc[mi][ni][reg];
            }
        }
    }
}

extern "C" void kernel_launch(void* const* d_in, const int* in_sizes, int n_in,
                              void* d_out, int out_size, void* d_ws, size_t ws_size,
                              hipStream_t stream)
{
    const float* x    = (const float*)d_in[0];
    const float* cosb = (const float*)d_in[1];
    const float* sinb = (const float*)d_in[2];
    const float* Wq   = (const float*)d_in[3];
    const float* Wk   = (const float*)d_in[4];
    const float* Wv   = (const float*)d_in[5];
    const float* Wo   = (const float*)d_in[6];
    float* out = (float*)d_out;

    unsigned short* xb   = (unsigned short*)d_ws;
    unsigned short* wqkv = xb + (size_t)MM * DIM;
    unsigned short* wob  = wqkv + (size_t)NQKV * DIM;
    unsigned short* qws  = wob + (size_t)DIM * DIM;
    unsigned short* kws  = qws + (size_t)BB * NH * LL * HD;
    unsigned short* vT   = kws + (size_t)BB * NH * LL * HD;
    unsigned short* aws  = xb;   // alias: xb dead after qkv_gemm

    convert_inputs<<<dim3(SEG / (256 * 8), 8), 256, 0, stream>>>(
        x, Wq, Wk, Wv, Wo, xb, wqkv, wob);
    qkv_gemm<<<dim3(NQKV / 128, MM / 128), 256, 0, stream>>>(
        xb, wqkv, cosb, sinb, qws, kws, vT);
    swa_attn<<<dim3(LL / 64, NH, BB), 256, 0, stream>>>(qws, kws, vT, aws);
    out_gemm<<<dim3(DIM / 64, MM / 128), 256, 0, stream>>>(aws, wob, out);
}

// Round 10
// 159.847 us; speedup vs baseline: 1.0420x; 1.0310x over previous
//
#include <hip/hip_runtime.h>

// SlidingWindowAttention: B=2, L=2048, D=1024, H=16, hd=64, W=256.
// I/O f32; internal bf16 MFMA with f32 accum.
#define DIM 1024
#define NH  16
#define HD  64
#define BB  2
#define LL  2048
#define WIN 256
#define MM  (BB * LL)     // 4096 rows
#define NQKV (3 * DIM)    // 3072 fused QKV output cols
#define SEG  (DIM * DIM)

typedef __bf16 bf16x8 __attribute__((ext_vector_type(8)));
typedef float  f32x4  __attribute__((ext_vector_type(4)));
typedef unsigned short u16x8 __attribute__((ext_vector_type(8)));

__device__ __forceinline__ unsigned short f2bf(float f) {
    union { float f; unsigned int i; } v; v.f = f;
    unsigned int r = v.i + 0x7fffu + ((v.i >> 16) & 1u);  // RNE
    return (unsigned short)(r >> 16);
}
__device__ __forceinline__ bf16x8 load8bf(const unsigned short* p) {
    uint4 u = *reinterpret_cast<const uint4*>(p);
    return __builtin_bit_cast(bf16x8, u);
}
__device__ __forceinline__ void gll16(const void* g, void* l) {
    __builtin_amdgcn_global_load_lds(
        (const __attribute__((address_space(1))) unsigned int*)g,
        (__attribute__((address_space(3))) unsigned int*)l, 16, 0, 0);
}

// ---------------------------------------------------------------------------
// Kernel 0: f32 -> bf16 conversion/packing.
// ---------------------------------------------------------------------------
__global__ __launch_bounds__(256) void convert_inputs(
    const float* __restrict__ x,
    const float* __restrict__ Wq, const float* __restrict__ Wk,
    const float* __restrict__ Wv, const float* __restrict__ Wo,
    unsigned short* __restrict__ xb,
    unsigned short* __restrict__ wqkv,
    unsigned short* __restrict__ wob)
{
    const int y = blockIdx.y;
    const size_t base = ((size_t)blockIdx.x * 256 + threadIdx.x) * 8;
    const float* src; unsigned short* dst;
    if (y < 4)       { src = x + (size_t)y * SEG;  dst = xb + (size_t)y * SEG; }
    else if (y == 4) { src = Wq; dst = wqkv; }
    else if (y == 5) { src = Wk; dst = wqkv + SEG; }
    else if (y == 6) { src = Wv; dst = wqkv + 2 * (size_t)SEG; }
    else             { src = Wo; dst = wob; }
    float4 a = ((const float4*)(src + base))[0];
    float4 b = ((const float4*)(src + base))[1];
    u16x8 r;
    r[0] = f2bf(a.x); r[1] = f2bf(a.y); r[2] = f2bf(a.z); r[3] = f2bf(a.w);
    r[4] = f2bf(b.x); r[5] = f2bf(b.y); r[6] = f2bf(b.z); r[7] = f2bf(b.w);
    *(u16x8*)(dst + base) = r;
}

// ---------------------------------------------------------------------------
// Kernel 1: fused QKV GEMM + RoPE. 128x128 tile, 4 waves (2x2), BK=64,
// launch_bounds(256,4) caps VGPR under 128. 8-chunk XOR swizzled staging.
// XCD-aware block remap: linear id % 8 ~ XCD (dispatch round-robin). Without
// remap, XCD = bx%8 -> each XCD touches all 32 x-stripes (8 MB > 4 MB L2,
// FETCH 47 MB). Remap gives each XCD 8 m-stripes x 12 n-stripes (2+3 MB).
// q,k -> [B,H,L,64] (RoPE fused); v -> [B,H,64,L] via 2-pass LDS transpose.
// ---------------------------------------------------------------------------
__global__ __launch_bounds__(256, 4) void qkv_gemm(
    const unsigned short* __restrict__ xb,
    const unsigned short* __restrict__ wqkv,
    const float* __restrict__ cosb, const float* __restrict__ sinb,
    unsigned short* __restrict__ qws, unsigned short* __restrict__ kws,
    unsigned short* __restrict__ vT)
{
    __shared__ __align__(16) unsigned short smem[2 * 128 * 64];  // As|Bs 32 KB
    unsigned short* As = smem;
    unsigned short* Bs = smem + 128 * 64;
    const int t = threadIdx.x;
    const int lane = t & 63, w = t >> 6;
    const int wm = w >> 1, wn = w & 1;
    const int lr = lane & 15, quad = lane >> 4;

    // ---- XCD-aware remap: per XCD 12 n-blocks x 8 m-blocks ----
    const int id   = blockIdx.y * 24 + blockIdx.x;   // 0..767 (all co-resident)
    const int xcd  = id & 7, slot = id >> 3;         // 96 slots per XCD
    const int bxn  = (xcd & 1) * 12 + (slot % 12);
    const int byn  = (xcd >> 1) * 8 + (slot / 12);
    const int n0 = bxn * 128, m0 = byn * 128;

    f32x4 acc[4][4];
    for (int i = 0; i < 4; i++) for (int j = 0; j < 4; j++) acc[i][j] = 0.0f;

    const int rsub = t >> 3;                 // 0..31
    const int csw  = (t & 7) ^ (rsub & 7);   // swizzled source chunk
    const int sw7  = lr & 7;                 // frag-read swizzle key

    for (int k0 = 0; k0 < DIM; k0 += 64) {
        __syncthreads();
        #pragma unroll
        for (int p = 0; p < 4; p++) {
            const int row = p * 32 + rsub;
            gll16(xb   + (size_t)(m0 + row) * DIM + k0 + csw * 8,
                  &As[p * 2048 + t * 8]);
            gll16(wqkv + (size_t)(n0 + row) * DIM + k0 + csw * 8,
                  &Bs[p * 2048 + t * 8]);
        }
        __syncthreads();
        #pragma unroll
        for (int kk = 0; kk < 2; kk++) {
            bf16x8 af[4], bfr[4];
            #pragma unroll
            for (int mi = 0; mi < 4; mi++) {
                const int R = wm * 64 + mi * 16 + lr;
                af[mi] = load8bf(&As[R * 64 + (((kk * 4 + quad) ^ sw7) * 8)]);
            }
            #pragma unroll
            for (int ni = 0; ni < 4; ni++) {
                const int R = wn * 64 + ni * 16 + lr;
                bfr[ni] = load8bf(&Bs[R * 64 + (((kk * 4 + quad) ^ sw7) * 8)]);
            }
            #pragma unroll
            for (int mi = 0; mi < 4; mi++)
                #pragma unroll
                for (int ni = 0; ni < 4; ni++)
                    acc[mi][ni] = __builtin_amdgcn_mfma_f32_16x16x32_bf16(
                        af[mi], bfr[ni], acc[mi][ni], 0, 0, 0);
        }
    }

    const int ng = n0 + wn * 64;
    const int which = ng >> 10;            // 0=q 1=k 2=v (wave-uniform)
    const int h = (ng & (DIM - 1)) >> 6;

    if (which == 2) {
        // ---- v: transpose 64x64 tile -> vT[B,H,64,L], 2 passes of 32 d-rows
        __syncthreads();
        unsigned short* T = smem + w * 2048;
        const int token0 = m0 + wm * 64;
        const int b  = token0 >> 11;
        const int lg = (token0 & (LL - 1)) + (lane & 7) * 8;
        #pragma unroll
        for (int p = 0; p < 2; p++) {
            #pragma unroll
            for (int ni = 2 * p; ni < 2 * p + 2; ni++) {
                const int dl = (ni & 1) * 16 + lr;
                const int g4 = (dl & 7) << 2;
                #pragma unroll
                for (int mi = 0; mi < 4; mi++)
                    #pragma unroll
                    for (int reg = 0; reg < 4; reg++) {
                        const int l = mi * 16 + quad * 4 + reg;
                        const int cw = (l >> 1) ^ g4;
                        T[dl * 64 + cw * 2 + (l & 1)] = f2bf(acc[mi][ni][reg]);
                    }
            }
            #pragma unroll
            for (int s = 0; s < 4; s++) {
                const int dl = s * 8 + (lane >> 3);
                const int d  = p * 32 + dl;
                const int g4 = (dl & 7) << 2;
                const int pd = ((lane & 7) * 4) ^ g4;
                uint4 val = *(const uint4*)&T[dl * 64 + pd * 2];
                *(uint4*)&vT[((size_t)(b * NH + h) * HD + d) * LL + lg] = val;
            }
        }
    } else {
        unsigned short* dst = (which == 0) ? qws : kws;
        #pragma unroll
        for (int mi = 0; mi < 4; mi++) {
            #pragma unroll
            for (int reg = 0; reg < 4; reg++) {
                const int row = m0 + wm * 64 + mi * 16 + quad * 4 + reg;
                const int b = row >> 11, l = row & (LL - 1);
                #pragma unroll
                for (int ni = 0; ni < 4; ni++) {
                    const int d = ni * 16 + lr;
                    const float c = cosb[l * HD + d];
                    const float s = sinb[l * HD + d];
                    const float partner = (d < 32) ? -acc[mi][ni + 2][reg]
                                                   :  acc[mi][ni - 2][reg];
                    dst[((size_t)(b * NH + h) * LL + l) * HD + d] =
                        f2bf(acc[mi][ni][reg] * c + partner * s);
                }
            }
        }
    }
}

// ---------------------------------------------------------------------------
// Kernel 2: sliding-window attention — online/streaming PV (round-9 version;
// three structurally different swa variants measured within noise -> near
// its floor). 4-wave block per 64 queries; K-span in 40 KB LDS; per-32-key
// chunk: scores -> exp -> tiny wave-private bf16 P -> immediate PV MFMA.
// ---------------------------------------------------------------------------
#define SW_SPAN 320
#define PSTR 40   // u16 row stride of chunk-P buffer (16B-aligned rows)
__global__ __launch_bounds__(256, 3) void swa_attn(
    const unsigned short* __restrict__ qws,
    const unsigned short* __restrict__ kws,
    const unsigned short* __restrict__ vT,
    unsigned short* __restrict__ aout)
{
    __shared__ __align__(16) unsigned short Ks[SW_SPAN * 64];   // 40 KB
    __shared__ __align__(16) unsigned short Pc[4][16][PSTR];    // 5 KB

    const int t = threadIdx.x;
    const int lane = t & 63, w = t >> 6;
    const int qb = blockIdx.x, h = blockIdx.y, b = blockIdx.z;
    const int q0 = qb * 64;
    const int base_key = q0 - WIN;

    const int lr = lane & 15, quad = lane >> 4, ko = quad * 8;
    const size_t base = ((size_t)(b * NH + h)) * LL * HD;
    const unsigned short* Q  = qws + base;
    const unsigned short* K  = kws + base;
    const unsigned short* VT = vT + base;     // [64][LL]

    {
        const int rsub = t >> 3;
        const int csw  = (t & 7) ^ (rsub & 7);
        #pragma unroll
        for (int p = 0; p < 10; p++) {
            const int j = min(max(base_key + p * 32 + rsub, 0), LL - 1);
            gll16(K + (size_t)j * HD + csw * 8, &Ks[p * 2048 + t * 8]);
        }
    }
    const int i0 = q0 + w * 16;               // wave's query tile
    const int wkey = i0 - WIN;                // wave's key-span start
    const bf16x8 qa0 = load8bf(Q + (size_t)(i0 + lr) * HD + ko);
    const bf16x8 qa1 = load8bf(Q + (size_t)(i0 + lr) * HD + 32 + ko);
    __syncthreads();                          // the only barrier

    float rowsum[4] = {0.f, 0.f, 0.f, 0.f};
    f32x4 o[4];
    #pragma unroll
    for (int nt = 0; nt < 4; nt++) o[nt] = 0.0f;

    #pragma unroll
    for (int kc = 0; kc < 9; kc++) {
        #pragma unroll
        for (int sub = 0; sub < 2; sub++) {
            const int kt = kc * 2 + sub;      // 0..17 (17 = pad tile)
            const int R = min(w * 16 + kt * 16 + lr, SW_SPAN - 1);
            const bf16x8 kb0 = load8bf(&Ks[R * 64 + ((quad       ^ (R & 7)) * 8)]);
            const bf16x8 kb1 = load8bf(&Ks[R * 64 + (((quad + 4) ^ (R & 7)) * 8)]);
            f32x4 s = 0.0f;
            s = __builtin_amdgcn_mfma_f32_16x16x32_bf16(qa0, kb0, s, 0, 0, 0);
            s = __builtin_amdgcn_mfma_f32_16x16x32_bf16(qa1, kb1, s, 0, 0, 0);
            #pragma unroll
            for (int reg = 0; reg < 4; reg++) {
                const int i = i0 + quad * 4 + reg;
                const int j = wkey + kt * 16 + lr;
                const bool valid = (j >= 0) && (j <= i) && (j >= i - WIN);
                const float e = valid ? __expf(s[reg] * 0.125f) : 0.0f;
                rowsum[reg] += e;
                Pc[w][quad * 4 + reg][sub * 16 + lr] = f2bf(e);
            }
        }
        const bf16x8 pa = load8bf(&Pc[w][lr][ko]);
        int kb = wkey + kc * 32 + ko;
        kb = min(max(kb, 0), LL - 8);         // clamp touches only P==0 cols
        bf16x8 bv[4];
        #pragma unroll
        for (int nt = 0; nt < 4; nt++)
            bv[nt] = load8bf(VT + (size_t)(nt * 16 + lr) * LL + kb);
        #pragma unroll
        for (int nt = 0; nt < 4; nt++)
            o[nt] = __builtin_amdgcn_mfma_f32_16x16x32_bf16(pa, bv[nt], o[nt], 0, 0, 0);
    }

    float inv[4];
    #pragma unroll
    for (int reg = 0; reg < 4; reg++) {       // 16-lane butterfly within quad
        float s = rowsum[reg];
        s += __shfl_xor(s, 1); s += __shfl_xor(s, 2);
        s += __shfl_xor(s, 4); s += __shfl_xor(s, 8);
        inv[reg] = 1.0f / s;
    }

    #pragma unroll
    for (int nt = 0; nt < 4; nt++) {
        #pragma unroll
        for (int reg = 0; reg < 4; reg++) {
            const int i = i0 + quad * 4 + reg;
            const int d = nt * 16 + lr;
            aout[((size_t)(b * LL + i)) * DIM + h * HD + d] =
                f2bf(o[nt][reg] * inv[reg]);
        }
    }
}

// ---------------------------------------------------------------------------
// Kernel 3: output projection. 64x64 tiles -> 1024 blocks (4/CU, was 2/CU at
// 128x64) for latency hiding; BK=64, swizzled staging; XCD-aware remap
// (per XCD 8 n x 16 m => 1+2 MB L2 working set). Wave = 32M x 32N.
// ---------------------------------------------------------------------------
__global__ __launch_bounds__(256, 4) void out_gemm(
    const unsigned short* __restrict__ A,
    const unsigned short* __restrict__ Wob,
    float* __restrict__ out)
{
    __shared__ __align__(16) unsigned short smem[64 * 64 + 64 * 64];  // 16 KB
    unsigned short* As = smem;
    unsigned short* Bs = smem + 64 * 64;
    const int t = threadIdx.x;
    const int lane = t & 63, w = t >> 6;
    const int wm = w >> 1, wn = w & 1;
    const int lr = lane & 15, quad = lane >> 4;

    // ---- XCD-aware remap: per XCD 8 bx x 16 by ----
    const int id   = blockIdx.y * 16 + blockIdx.x;   // 0..1023 (all co-resident)
    const int xcd  = id & 7, slot = id >> 3;         // 128 slots per XCD
    const int bx   = (xcd & 1) * 8 + (slot & 7);
    const int by   = (xcd >> 1) * 16 + (slot >> 3);
    const int n0 = bx * 64, m0 = by * 64;

    f32x4 acc[2][2];
    for (int i = 0; i < 2; i++) for (int j = 0; j < 2; j++) acc[i][j] = 0.0f;

    const int rsub = t >> 3;
    const int csw  = (t & 7) ^ (rsub & 7);
    const int sw7  = lr & 7;

    for (int k0 = 0; k0 < DIM; k0 += 64) {
        __syncthreads();
        #pragma unroll
        for (int p = 0; p < 2; p++) {
            const int row = p * 32 + rsub;
            gll16(A   + (size_t)(m0 + row) * DIM + k0 + csw * 8,
                  &As[p * 2048 + t * 8]);
            gll16(Wob + (size_t)(n0 + row) * DIM + k0 + csw * 8,
                  &Bs[p * 2048 + t * 8]);
        }
        __syncthreads();
        #pragma unroll
        for (int kk = 0; kk < 2; kk++) {
            bf16x8 af[2], bfr[2];
            #pragma unroll
            for (int mi = 0; mi < 2; mi++) {
                const int R = wm * 32 + mi * 16 + lr;
                af[mi] = load8bf(&As[R * 64 + (((kk * 4 + quad) ^ sw7) * 8)]);
            }
            #pragma unroll
            for (int ni = 0; ni < 2; ni++) {
                const int R = wn * 32 + ni * 16 + lr;
                bfr[ni] = load8bf(&Bs[R * 64 + (((kk * 4 + quad) ^ sw7) * 8)]);
            }
            #pragma unroll
            for (int mi = 0; mi < 2; mi++)
                #pragma unroll
                for (int ni = 0; ni < 2; ni++)
                    acc[mi][ni] = __builtin_amdgcn_mfma_f32_16x16x32_bf16(
                        af[mi], bfr[ni], acc[mi][ni], 0, 0, 0);
        }
    }

    #pragma unroll
    for (int mi = 0; mi < 2; mi++) {
        #pragma unroll
        for (int reg = 0; reg < 4; reg++) {
            const int row = m0 + wm * 32 + mi * 16 + quad * 4 + reg;
            #pragma unroll
            for (int ni = 0; ni < 2; ni++) {
                const int col = n0 + wn * 32 + ni * 16 + lr;
                out[(size_t)row * DIM + col] = acc[mi][ni][reg];
            }
        }
    }
}

extern "C" void kernel_launch(void* const* d_in, const int* in_sizes, int n_in,
                              void* d_out, int out_size, void* d_ws, size_t ws_size,
                              hipStream_t stream)
{
    const float* x    = (const float*)d_in[0];
    const float* cosb = (const float*)d_in[1];
    const float* sinb = (const float*)d_in[2];
    const float* Wq   = (const float*)d_in[3];
    const float* Wk   = (const float*)d_in[4];
    const float* Wv   = (const float*)d_in[5];
    const float* Wo   = (const float*)d_in[6];
    float* out = (float*)d_out;

    unsigned short* xb   = (unsigned short*)d_ws;
    unsigned short* wqkv = xb + (size_t)MM * DIM;
    unsigned short* wob  = wqkv + (size_t)NQKV * DIM;
    unsigned short* qws  = wob + (size_t)DIM * DIM;
    unsigned short* kws  = qws + (size_t)BB * NH * LL * HD;
    unsigned short* vT   = kws + (size_t)BB * NH * LL * HD;
    unsigned short* aws  = xb;   // alias: xb dead after qkv_gemm

    convert_inputs<<<dim3(SEG / (256 * 8), 8), 256, 0, stream>>>(
        x, Wq, Wk, Wv, Wo, xb, wqkv, wob);
    qkv_gemm<<<dim3(NQKV / 128, MM / 128), 256, 0, stream>>>(
        xb, wqkv, cosb, sinb, qws, kws, vT);
    swa_attn<<<dim3(LL / 64, NH, BB), 256, 0, stream>>>(qws, kws, vT, aws);
    out_gemm<<<dim3(DIM / 64, MM / 64), 256, 0, stream>>>(aws, wob, out);
}

// Round 11
// 155.682 us; speedup vs baseline: 1.0699x; 1.0268x over previous
//
#include <hip/hip_runtime.h>

// SlidingWindowAttention: B=2, L=2048, D=1024, H=16, hd=64, W=256.
// I/O f32; internal bf16 MFMA with f32 accum.
#define DIM 1024
#define NH  16
#define HD  64
#define BB  2
#define LL  2048
#define WIN 256
#define MM  (BB * LL)     // 4096 rows
#define NQKV (3 * DIM)    // 3072 fused QKV output cols
#define SEG  (DIM * DIM)

typedef __bf16 bf16x8 __attribute__((ext_vector_type(8)));
typedef float  f32x4  __attribute__((ext_vector_type(4)));
typedef unsigned short u16x8 __attribute__((ext_vector_type(8)));

__device__ __forceinline__ unsigned short f2bf(float f) {
    union { float f; unsigned int i; } v; v.f = f;
    unsigned int r = v.i + 0x7fffu + ((v.i >> 16) & 1u);  // RNE
    return (unsigned short)(r >> 16);
}
__device__ __forceinline__ bf16x8 load8bf(const unsigned short* p) {
    uint4 u = *reinterpret_cast<const uint4*>(p);
    return __builtin_bit_cast(bf16x8, u);
}
__device__ __forceinline__ void gll16(const void* g, void* l) {
    __builtin_amdgcn_global_load_lds(
        (const __attribute__((address_space(1))) unsigned int*)g,
        (__attribute__((address_space(3))) unsigned int*)l, 16, 0, 0);
}

// ---------------------------------------------------------------------------
// Kernel 0: f32 -> bf16 conversion/packing.
// ---------------------------------------------------------------------------
__global__ __launch_bounds__(256) void convert_inputs(
    const float* __restrict__ x,
    const float* __restrict__ Wq, const float* __restrict__ Wk,
    const float* __restrict__ Wv, const float* __restrict__ Wo,
    unsigned short* __restrict__ xb,
    unsigned short* __restrict__ wqkv,
    unsigned short* __restrict__ wob)
{
    const int y = blockIdx.y;
    const size_t base = ((size_t)blockIdx.x * 256 + threadIdx.x) * 8;
    const float* src; unsigned short* dst;
    if (y < 4)       { src = x + (size_t)y * SEG;  dst = xb + (size_t)y * SEG; }
    else if (y == 4) { src = Wq; dst = wqkv; }
    else if (y == 5) { src = Wk; dst = wqkv + SEG; }
    else if (y == 6) { src = Wv; dst = wqkv + 2 * (size_t)SEG; }
    else             { src = Wo; dst = wob; }
    float4 a = ((const float4*)(src + base))[0];
    float4 b = ((const float4*)(src + base))[1];
    u16x8 r;
    r[0] = f2bf(a.x); r[1] = f2bf(a.y); r[2] = f2bf(a.z); r[3] = f2bf(a.w);
    r[4] = f2bf(b.x); r[5] = f2bf(b.y); r[6] = f2bf(b.z); r[7] = f2bf(b.w);
    *(u16x8*)(dst + base) = r;
}

// ---------------------------------------------------------------------------
// Kernel 1: fused QKV GEMM + RoPE. 128x128 tile, 4 waves (2x2), BK=64,
// launch_bounds(256,4), 8-chunk XOR swizzled staging, XCD-aware remap.
// q,k -> [B,H,L,64] (RoPE fused); v -> [B,H,64,L] via 2-pass LDS transpose.
// ---------------------------------------------------------------------------
__global__ __launch_bounds__(256, 4) void qkv_gemm(
    const unsigned short* __restrict__ xb,
    const unsigned short* __restrict__ wqkv,
    const float* __restrict__ cosb, const float* __restrict__ sinb,
    unsigned short* __restrict__ qws, unsigned short* __restrict__ kws,
    unsigned short* __restrict__ vT)
{
    __shared__ __align__(16) unsigned short smem[2 * 128 * 64];  // As|Bs 32 KB
    unsigned short* As = smem;
    unsigned short* Bs = smem + 128 * 64;
    const int t = threadIdx.x;
    const int lane = t & 63, w = t >> 6;
    const int wm = w >> 1, wn = w & 1;
    const int lr = lane & 15, quad = lane >> 4;

    // ---- XCD-aware remap: per XCD 12 n-blocks x 8 m-blocks ----
    const int id   = blockIdx.y * 24 + blockIdx.x;   // 0..767
    const int xcd  = id & 7, slot = id >> 3;         // 96 slots per XCD
    const int bxn  = (xcd & 1) * 12 + (slot % 12);
    const int byn  = (xcd >> 1) * 8 + (slot / 12);
    const int n0 = bxn * 128, m0 = byn * 128;

    f32x4 acc[4][4];
    for (int i = 0; i < 4; i++) for (int j = 0; j < 4; j++) acc[i][j] = 0.0f;

    const int rsub = t >> 3;                 // 0..31
    const int csw  = (t & 7) ^ (rsub & 7);   // swizzled source chunk
    const int sw7  = lr & 7;                 // frag-read swizzle key

    for (int k0 = 0; k0 < DIM; k0 += 64) {
        __syncthreads();
        #pragma unroll
        for (int p = 0; p < 4; p++) {
            const int row = p * 32 + rsub;
            gll16(xb   + (size_t)(m0 + row) * DIM + k0 + csw * 8,
                  &As[p * 2048 + t * 8]);
            gll16(wqkv + (size_t)(n0 + row) * DIM + k0 + csw * 8,
                  &Bs[p * 2048 + t * 8]);
        }
        __syncthreads();
        #pragma unroll
        for (int kk = 0; kk < 2; kk++) {
            bf16x8 af[4], bfr[4];
            #pragma unroll
            for (int mi = 0; mi < 4; mi++) {
                const int R = wm * 64 + mi * 16 + lr;
                af[mi] = load8bf(&As[R * 64 + (((kk * 4 + quad) ^ sw7) * 8)]);
            }
            #pragma unroll
            for (int ni = 0; ni < 4; ni++) {
                const int R = wn * 64 + ni * 16 + lr;
                bfr[ni] = load8bf(&Bs[R * 64 + (((kk * 4 + quad) ^ sw7) * 8)]);
            }
            #pragma unroll
            for (int mi = 0; mi < 4; mi++)
                #pragma unroll
                for (int ni = 0; ni < 4; ni++)
                    acc[mi][ni] = __builtin_amdgcn_mfma_f32_16x16x32_bf16(
                        af[mi], bfr[ni], acc[mi][ni], 0, 0, 0);
        }
    }

    const int ng = n0 + wn * 64;
    const int which = ng >> 10;            // 0=q 1=k 2=v (wave-uniform)
    const int h = (ng & (DIM - 1)) >> 6;

    if (which == 2) {
        __syncthreads();
        unsigned short* T = smem + w * 2048;
        const int token0 = m0 + wm * 64;
        const int b  = token0 >> 11;
        const int lg = (token0 & (LL - 1)) + (lane & 7) * 8;
        #pragma unroll
        for (int p = 0; p < 2; p++) {
            #pragma unroll
            for (int ni = 2 * p; ni < 2 * p + 2; ni++) {
                const int dl = (ni & 1) * 16 + lr;
                const int g4 = (dl & 7) << 2;
                #pragma unroll
                for (int mi = 0; mi < 4; mi++)
                    #pragma unroll
                    for (int reg = 0; reg < 4; reg++) {
                        const int l = mi * 16 + quad * 4 + reg;
                        const int cw = (l >> 1) ^ g4;
                        T[dl * 64 + cw * 2 + (l & 1)] = f2bf(acc[mi][ni][reg]);
                    }
            }
            #pragma unroll
            for (int s = 0; s < 4; s++) {
                const int dl = s * 8 + (lane >> 3);
                const int d  = p * 32 + dl;
                const int g4 = (dl & 7) << 2;
                const int pd = ((lane & 7) * 4) ^ g4;
                uint4 val = *(const uint4*)&T[dl * 64 + pd * 2];
                *(uint4*)&vT[((size_t)(b * NH + h) * HD + d) * LL + lg] = val;
            }
        }
    } else {
        unsigned short* dst = (which == 0) ? qws : kws;
        #pragma unroll
        for (int mi = 0; mi < 4; mi++) {
            #pragma unroll
            for (int reg = 0; reg < 4; reg++) {
                const int row = m0 + wm * 64 + mi * 16 + quad * 4 + reg;
                const int b = row >> 11, l = row & (LL - 1);
                #pragma unroll
                for (int ni = 0; ni < 4; ni++) {
                    const int d = ni * 16 + lr;
                    const float c = cosb[l * HD + d];
                    const float s = sinb[l * HD + d];
                    const float partner = (d < 32) ? -acc[mi][ni + 2][reg]
                                                   :  acc[mi][ni - 2][reg];
                    dst[((size_t)(b * NH + h) * LL + l) * HD + d] =
                        f2bf(acc[mi][ni][reg] * c + partner * s);
                }
            }
        }
    }
}

// ---------------------------------------------------------------------------
// Kernel 2: sliding-window attention — streaming PV, de-masked fast path.
// Round-10 PMC: 45.6 us, MfmaUtil 3.7%, VALUBusy 16%, FETCH 46.5 MB (vs 8 MB
// unique K). Fixes:
//  (a) mask algebra: for q0>=WIN, tiles kt=1..15 are fully valid (no mask),
//      kt=0 needs lr>=quad*4+reg, kt=16 needs lr<=quad*4+reg (loop-invariant
//      bools), kt=17 entirely masked -> skip MFMA+exp, zero P cols.
//  (b) XCD remap: each XCD owns 4 (h,b) rows x all qb -> adjacent qb (80%
//      K-overlap) share that XCD's L2 (~2.3 MB working set).
//  (c) V loads software-pipelined one chunk ahead.
// ---------------------------------------------------------------------------
#define SW_SPAN 320
#define PSTR 40   // u16 row stride of chunk-P buffer (16B-aligned rows)
__global__ __launch_bounds__(256, 3) void swa_attn(
    const unsigned short* __restrict__ qws,
    const unsigned short* __restrict__ kws,
    const unsigned short* __restrict__ vT,
    unsigned short* __restrict__ aout)
{
    __shared__ __align__(16) unsigned short Ks[SW_SPAN * 64];   // 40 KB
    __shared__ __align__(16) unsigned short Pc[4][16][PSTR];    // 5 KB

    const int t = threadIdx.x;
    const int lane = t & 63, w = t >> 6;

    // ---- XCD remap: xcd = id%8 (dispatch RR); each XCD: 4 hb-rows x 32 qb
    const int id   = (blockIdx.z * 16 + blockIdx.y) * 32 + blockIdx.x;
    const int xcd  = id & 7, slot = id >> 3;        // slot 0..127
    const int hb   = xcd * 4 + (slot >> 5);         // 0..31
    const int qb   = slot & 31;
    const int h = hb & 15, b = hb >> 4;

    const int q0 = qb * 64;
    const int base_key = q0 - WIN;

    const int lr = lane & 15, quad = lane >> 4, ko = quad * 8;
    const size_t base = ((size_t)(b * NH + h)) * LL * HD;
    const unsigned short* Q  = qws + base;
    const unsigned short* K  = kws + base;
    const unsigned short* VT = vT + base;     // [64][LL]

    {
        const int rsub = t >> 3;
        const int csw  = (t & 7) ^ (rsub & 7);
        #pragma unroll
        for (int p = 0; p < 10; p++) {
            const int j = min(max(base_key + p * 32 + rsub, 0), LL - 1);
            gll16(K + (size_t)j * HD + csw * 8, &Ks[p * 2048 + t * 8]);
        }
    }
    const int i0 = q0 + w * 16;               // wave's query tile
    const int wkey = i0 - WIN;                // wave's key-span start
    const bf16x8 qa0 = load8bf(Q + (size_t)(i0 + lr) * HD + ko);
    const bf16x8 qa1 = load8bf(Q + (size_t)(i0 + lr) * HD + 32 + ko);
    __syncthreads();                          // the only barrier

    float rowsum[4] = {0.f, 0.f, 0.f, 0.f};
    f32x4 o[4];
    #pragma unroll
    for (int nt = 0; nt < 4; nt++) o[nt] = 0.0f;

    if (q0 >= WIN) {
        // ================= fast path: wkey >= 0 =================
        bool mlo[4], mhi[4];
        #pragma unroll
        for (int reg = 0; reg < 4; reg++) {
            mlo[reg] = (lr >= quad * 4 + reg);   // kt=0 validity
            mhi[reg] = (lr <= quad * 4 + reg);   // kt=16 validity
        }
        bf16x8 bv[4];
        #pragma unroll
        for (int nt = 0; nt < 4; nt++)           // V chunk 0 (no clamp needed)
            bv[nt] = load8bf(VT + (size_t)(nt * 16 + lr) * LL + wkey + ko);

        #pragma unroll
        for (int kc = 0; kc < 9; kc++) {
            #pragma unroll
            for (int sub = 0; sub < 2; sub++) {
                const int kt = 2 * kc + sub;
                if (kt > 16) {                   // kt=17: all-masked pad tile
                    #pragma unroll
                    for (int reg = 0; reg < 4; reg++)
                        Pc[w][quad * 4 + reg][16 + lr] = 0;
                } else {
                    const int R = w * 16 + kt * 16 + lr;
                    const bf16x8 kb0 = load8bf(&Ks[R * 64 + ((quad       ^ (R & 7)) * 8)]);
                    const bf16x8 kb1 = load8bf(&Ks[R * 64 + (((quad + 4) ^ (R & 7)) * 8)]);
                    f32x4 s = 0.0f;
                    s = __builtin_amdgcn_mfma_f32_16x16x32_bf16(qa0, kb0, s, 0, 0, 0);
                    s = __builtin_amdgcn_mfma_f32_16x16x32_bf16(qa1, kb1, s, 0, 0, 0);
                    #pragma unroll
                    for (int reg = 0; reg < 4; reg++) {
                        float e = __expf(s[reg] * 0.125f);
                        if (kt == 0)  e = mlo[reg] ? e : 0.0f;
                        if (kt == 16) e = mhi[reg] ? e : 0.0f;
                        rowsum[reg] += e;
                        Pc[w][quad * 4 + reg][sub * 16 + lr] = f2bf(e);
                    }
                }
            }
            bf16x8 bvn[4];
            if (kc < 8) {                        // prefetch next V chunk
                int kb = wkey + (kc + 1) * 32 + ko;
                kb = min(kb, LL - 8);            // tail clamp: P==0 there
                #pragma unroll
                for (int nt = 0; nt < 4; nt++)
                    bvn[nt] = load8bf(VT + (size_t)(nt * 16 + lr) * LL + kb);
            }
            const bf16x8 pa = load8bf(&Pc[w][lr][ko]);
            #pragma unroll
            for (int nt = 0; nt < 4; nt++)
                o[nt] = __builtin_amdgcn_mfma_f32_16x16x32_bf16(pa, bv[nt], o[nt], 0, 0, 0);
            if (kc < 8) {
                #pragma unroll
                for (int nt = 0; nt < 4; nt++) bv[nt] = bvn[nt];
            }
        }
    } else {
        // ================= slow path (q0 < WIN): full masks =================
        #pragma unroll
        for (int kc = 0; kc < 9; kc++) {
            #pragma unroll
            for (int sub = 0; sub < 2; sub++) {
                const int kt = 2 * kc + sub;
                const int R = min(w * 16 + kt * 16 + lr, SW_SPAN - 1);
                const bf16x8 kb0 = load8bf(&Ks[R * 64 + ((quad       ^ (R & 7)) * 8)]);
                const bf16x8 kb1 = load8bf(&Ks[R * 64 + (((quad + 4) ^ (R & 7)) * 8)]);
                f32x4 s = 0.0f;
                s = __builtin_amdgcn_mfma_f32_16x16x32_bf16(qa0, kb0, s, 0, 0, 0);
                s = __builtin_amdgcn_mfma_f32_16x16x32_bf16(qa1, kb1, s, 0, 0, 0);
                #pragma unroll
                for (int reg = 0; reg < 4; reg++) {
                    const int i = i0 + quad * 4 + reg;
                    const int j = wkey + kt * 16 + lr;
                    const bool valid = (j >= 0) && (j <= i) && (j >= i - WIN);
                    const float e = valid ? __expf(s[reg] * 0.125f) : 0.0f;
                    rowsum[reg] += e;
                    Pc[w][quad * 4 + reg][sub * 16 + lr] = f2bf(e);
                }
            }
            const bf16x8 pa = load8bf(&Pc[w][lr][ko]);
            int kb = wkey + kc * 32 + ko;
            kb = min(max(kb, 0), LL - 8);
            bf16x8 bv[4];
            #pragma unroll
            for (int nt = 0; nt < 4; nt++)
                bv[nt] = load8bf(VT + (size_t)(nt * 16 + lr) * LL + kb);
            #pragma unroll
            for (int nt = 0; nt < 4; nt++)
                o[nt] = __builtin_amdgcn_mfma_f32_16x16x32_bf16(pa, bv[nt], o[nt], 0, 0, 0);
        }
    }

    float inv[4];
    #pragma unroll
    for (int reg = 0; reg < 4; reg++) {       // 16-lane butterfly within quad
        float s = rowsum[reg];
        s += __shfl_xor(s, 1); s += __shfl_xor(s, 2);
        s += __shfl_xor(s, 4); s += __shfl_xor(s, 8);
        inv[reg] = 1.0f / s;
    }

    #pragma unroll
    for (int nt = 0; nt < 4; nt++) {
        #pragma unroll
        for (int reg = 0; reg < 4; reg++) {
            const int i = i0 + quad * 4 + reg;
            const int d = nt * 16 + lr;
            aout[((size_t)(b * LL + i)) * DIM + h * HD + d] =
                f2bf(o[nt][reg] * inv[reg]);
        }
    }
}

// ---------------------------------------------------------------------------
// Kernel 3: output projection. 64x64 tiles -> 1024 blocks (4/CU), BK=64,
// swizzled staging, XCD-aware remap. Wave = 32M x 32N.
// ---------------------------------------------------------------------------
__global__ __launch_bounds__(256, 4) void out_gemm(
    const unsigned short* __restrict__ A,
    const unsigned short* __restrict__ Wob,
    float* __restrict__ out)
{
    __shared__ __align__(16) unsigned short smem[64 * 64 + 64 * 64];  // 16 KB
    unsigned short* As = smem;
    unsigned short* Bs = smem + 64 * 64;
    const int t = threadIdx.x;
    const int lane = t & 63, w = t >> 6;
    const int wm = w >> 1, wn = w & 1;
    const int lr = lane & 15, quad = lane >> 4;

    const int id   = blockIdx.y * 16 + blockIdx.x;   // 0..1023
    const int xcd  = id & 7, slot = id >> 3;         // 128 slots per XCD
    const int bx   = (xcd & 1) * 8 + (slot & 7);
    const int by   = (xcd >> 1) * 16 + (slot >> 3);
    const int n0 = bx * 64, m0 = by * 64;

    f32x4 acc[2][2];
    for (int i = 0; i < 2; i++) for (int j = 0; j < 2; j++) acc[i][j] = 0.0f;

    const int rsub = t >> 3;
    const int csw  = (t & 7) ^ (rsub & 7);
    const int sw7  = lr & 7;

    for (int k0 = 0; k0 < DIM; k0 += 64) {
        __syncthreads();
        #pragma unroll
        for (int p = 0; p < 2; p++) {
            const int row = p * 32 + rsub;
            gll16(A   + (size_t)(m0 + row) * DIM + k0 + csw * 8,
                  &As[p * 2048 + t * 8]);
            gll16(Wob + (size_t)(n0 + row) * DIM + k0 + csw * 8,
                  &Bs[p * 2048 + t * 8]);
        }
        __syncthreads();
        #pragma unroll
        for (int kk = 0; kk < 2; kk++) {
            bf16x8 af[2], bfr[2];
            #pragma unroll
            for (int mi = 0; mi < 2; mi++) {
                const int R = wm * 32 + mi * 16 + lr;
                af[mi] = load8bf(&As[R * 64 + (((kk * 4 + quad) ^ sw7) * 8)]);
            }
            #pragma unroll
            for (int ni = 0; ni < 2; ni++) {
                const int R = wn * 32 + ni * 16 + lr;
                bfr[ni] = load8bf(&Bs[R * 64 + (((kk * 4 + quad) ^ sw7) * 8)]);
            }
            #pragma unroll
            for (int mi = 0; mi < 2; mi++)
                #pragma unroll
                for (int ni = 0; ni < 2; ni++)
                    acc[mi][ni] = __builtin_amdgcn_mfma_f32_16x16x32_bf16(
                        af[mi], bfr[ni], acc[mi][ni], 0, 0, 0);
        }
    }

    #pragma unroll
    for (int mi = 0; mi < 2; mi++) {
        #pragma unroll
        for (int reg = 0; reg < 4; reg++) {
            const int row = m0 + wm * 32 + mi * 16 + quad * 4 + reg;
            #pragma unroll
            for (int ni = 0; ni < 2; ni++) {
                const int col = n0 + wn * 32 + ni * 16 + lr;
                out[(size_t)row * DIM + col] = acc[mi][ni][reg];
            }
        }
    }
}

extern "C" void kernel_launch(void* const* d_in, const int* in_sizes, int n_in,
                              void* d_out, int out_size, void* d_ws, size_t ws_size,
                              hipStream_t stream)
{
    const float* x    = (const float*)d_in[0];
    const float* cosb = (const float*)d_in[1];
    const float* sinb = (const float*)d_in[2];
    const float* Wq   = (const float*)d_in[3];
    const float* Wk   = (const float*)d_in[4];
    const float* Wv   = (const float*)d_in[5];
    const float* Wo   = (const float*)d_in[6];
    float* out = (float*)d_out;

    unsigned short* xb   = (unsigned short*)d_ws;
    unsigned short* wqkv = xb + (size_t)MM * DIM;
    unsigned short* wob  = wqkv + (size_t)NQKV * DIM;
    unsigned short* qws  = wob + (size_t)DIM * DIM;
    unsigned short* kws  = qws + (size_t)BB * NH * LL * HD;
    unsigned short* vT   = kws + (size_t)BB * NH * LL * HD;
    unsigned short* aws  = xb;   // alias: xb dead after qkv_gemm

    convert_inputs<<<dim3(SEG / (256 * 8), 8), 256, 0, stream>>>(
        x, Wq, Wk, Wv, Wo, xb, wqkv, wob);
    qkv_gemm<<<dim3(NQKV / 128, MM / 128), 256, 0, stream>>>(
        xb, wqkv, cosb, sinb, qws, kws, vT);
    swa_attn<<<dim3(LL / 64, NH, BB), 256, 0, stream>>>(qws, kws, vT, aws);
    out_gemm<<<dim3(DIM / 64, MM / 64), 256, 0, stream>>>(aws, wob, out);
}